// Round 8
// baseline (493.322 us; speedup 1.0000x reference)
//
#include <hip/hip_runtime.h>
#include <cstdint>
#include <cstddef>

// ---------------------------------------------------------------------------
// ReweightGNN: 3x GraphSAGE-reweight (lmda=1.0) + dropout(0.5) + 2-layer MLP
// N=50000, E=800000, D=128, DOUT=10. Outputs: h [N,128] fp32, y [N,10] fp32.
// R8: (a) agg fused INTO the layer GEMM (block gathers its 64 rows to LDS,
//     then MFMA; gather/MFMA phases of different blocks overlap across pipes);
//     (b) mask gen co-scheduled with truly idle-VALU partners: mw0 in scatter
//     (VALUBusy 1%), mw1+mw2 in fused layer1 (hidden under MFMA);
//     (c) R7's GEMM B-register hoist reverted (VGPR/occupancy regression).
// ---------------------------------------------------------------------------

#define N_NODES 50000
#define N_EDGES 800000
#define DGN 128
#define DOUT 10
#define NELEM (N_NODES * DGN)       // 6,400,000
#define NMASKW (NELEM / 64)         // 100,000 uint64 words per mask
#define NBINS 391                   // ceil(50000/128) coarse bins (row>>7)
#define TILE 4096                   // edges per scatter block
#define NTILES ((N_EDGES + TILE - 1) / TILE)   // 196
#define GBF ((N_NODES + 63) / 64)   // 782 fused-layer blocks
#define MK_BLOCKS 25000             // mask blocks (6.4M elems / 256)

// mega-kernel block ranges
#define XB_BLK 6250                 // x fp32->bf16 (1.6M float4)
#define HI_BLK NTILES               // 196 hist tiles
#define WC_BLK 128                  // W_comb = W_lin @ W_agg_top (2 mats)
#define TR_BLK 192                  // bottom transposes + Tm1 (49152 elems)
#define R0 XB_BLK
#define R1 (R0 + HI_BLK)
#define R2 (R1 + WC_BLK)
#define R3 (R2 + TR_BLK)
#define MEGA_BLOCKS (R3 + 1)        // +1 bvec block

typedef __attribute__((ext_vector_type(8))) short bf16x8;
typedef __attribute__((ext_vector_type(4))) float f32x4;

__host__ __device__ static inline unsigned short f2bf(float f) {
  union { float f; unsigned u; } c; c.f = f;
  unsigned u = c.u;
  return (unsigned short)((u + 0x7fffu + ((u >> 16) & 1u)) >> 16);  // RNE
}
__device__ static inline float bflo(unsigned u) { return __uint_as_float(u << 16); }
__device__ static inline float bfhi(unsigned u) { return __uint_as_float(u & 0xffff0000u); }

// ---------------------------------------------------------------------------
// threefry2x32 (exact JAX)
// ---------------------------------------------------------------------------
__host__ __device__ static inline void tf2x32(unsigned k0, unsigned k1,
                                              unsigned c0, unsigned c1,
                                              unsigned& o0, unsigned& o1) {
  unsigned ks2 = k0 ^ k1 ^ 0x1BD11BDAu;
  unsigned x0 = c0 + k0;
  unsigned x1 = c1 + k1;
#define TFR(r) { x0 += x1; x1 = (x1 << (r)) | (x1 >> (32 - (r))); x1 ^= x0; }
  TFR(13) TFR(15) TFR(26) TFR(6)
  x0 += k1;  x1 += ks2 + 1u;
  TFR(17) TFR(29) TFR(16) TFR(24)
  x0 += ks2; x1 += k0 + 2u;
  TFR(13) TFR(15) TFR(26) TFR(6)
  x0 += k0;  x1 += k1 + 3u;
  TFR(17) TFR(29) TFR(16) TFR(24)
  x0 += k1;  x1 += ks2 + 4u;
  TFR(13) TFR(15) TFR(26) TFR(6)
  x0 += ks2; x1 += k0 + 5u;
#undef TFR
  o0 = x0; o1 = x1;
}

// ---------------------------------------------------------------------------
// Mega prep kernel: x convert | hist | W_comb | transposes | bvec
// ---------------------------------------------------------------------------
__global__ __launch_bounds__(256) void mega_kernel(
    const float* __restrict__ x, unsigned short* __restrict__ xb,
    const int* __restrict__ ei, int* __restrict__ chist,
    const float* __restrict__ Wli, const float* __restrict__ Wai,
    const float* __restrict__ Wlh, const float* __restrict__ Wah,
    const float* __restrict__ Wm1,
    const float* __restrict__ bli, const float* __restrict__ blh,
    unsigned short* __restrict__ Tai, unsigned short* __restrict__ Tah,
    unsigned short* __restrict__ Tm1,
    float* __restrict__ bvi, float* __restrict__ bvh) {
  __shared__ int h[NBINS];
  const int b = blockIdx.x;
  const int tid = threadIdx.x;

  if (b < R0) {                       // ---- x convert ----
    int g = b * 256 + tid;
    float4 v = ((const float4*)x)[g];
    ushort4 o;
    o.x = f2bf(v.x); o.y = f2bf(v.y); o.z = f2bf(v.z); o.w = f2bf(v.w);
    ((ushort4*)xb)[g] = o;
  } else if (b < R1) {                // ---- hist ----
    for (int i = tid; i < NBINS; i += 256) h[i] = 0;
    __syncthreads();
    const int e0 = (b - R0) * TILE;
#pragma unroll 4
    for (int j = 0; j < TILE; j += 256) {
      int e = e0 + j + tid;
      if (e < N_EDGES) {
        int r = ei[e];
        r = (r < 0) ? 0 : (r >= N_NODES ? N_NODES - 1 : r);
        atomicAdd(&h[r >> 7], 1);
      }
    }
    __syncthreads();
    for (int i = tid; i < NBINS; i += 256)
      if (h[i]) atomicAdd(&chist[i], h[i]);
  } else if (b < R2) {                // ---- W_comb (fp32 accumulate) ----
    int idx = (b - R1) * 256 + tid;   // [0, 32768)
    int n = idx & 127;
    int k = (idx >> 7) & 127;
    int m = idx >> 14;                // 0: in-layer, 1: hidden
    const float* Wl = m ? Wlh : Wli;
    const float* Wa = m ? Wah : Wai;
    unsigned short* T = m ? Tah : Tai;
    float acc = 0.0f;
#pragma unroll 8
    for (int j = 0; j < 128; ++j)
      acc += Wl[k * 128 + j] * Wa[j * 128 + n];
    T[n * 256 + k] = f2bf(acc);
  } else if (b < R3) {                // ---- transposes ----
    int j = (b - R2) * 256 + tid;     // [0, 49152)
    if (j < 16384) {
      int kk = j & 127, n = j >> 7;
      Tai[n * 256 + 128 + kk] = f2bf(Wai[(size_t)(128 + kk) * 128 + n]);
    } else if (j < 32768) {
      int q = j - 16384;
      int kk = q & 127, n = q >> 7;
      Tah[n * 256 + 128 + kk] = f2bf(Wah[(size_t)(128 + kk) * 128 + n]);
    } else {
      int q = j - 32768;
      int k = q & 127, n = q >> 7;
      Tm1[n * 128 + k] = f2bf(Wm1[(size_t)k * 128 + n]);
    }
  } else {                            // ---- bvec ----
    int n = tid & 127;
    const float* bl = (tid < 128) ? bli : blh;
    const float* Wa = (tid < 128) ? Wai : Wah;
    float acc = 0.0f;
    for (int j = 0; j < 128; ++j) acc += bl[j] * Wa[j * 128 + n];
    if (tid < 128) bvi[n] = acc; else bvh[n] = acc;
  }
}

// ---------------------------------------------------------------------------
// CSR build phases 2-4 (verified R5/R6). scatter also hosts mw0 mask blocks.
// ---------------------------------------------------------------------------
__global__ __launch_bounds__(512) void prefix_kernel(const int* __restrict__ chist,
                                                     int* __restrict__ cbase,
                                                     int* __restrict__ ccursor,
                                                     int* __restrict__ rowptr) {
  __shared__ int s[512];
  const int t = threadIdx.x;
  int v = (t < NBINS) ? chist[t] : 0;
  s[t] = v;
  __syncthreads();
  for (int off = 1; off < 512; off <<= 1) {
    int tv = (t >= off) ? s[t - off] : 0;
    __syncthreads();
    s[t] += tv;
    __syncthreads();
  }
  if (t <= NBINS) {
    int ex = (t == 0) ? 0 : s[t - 1];
    cbase[t] = ex;
    if (t < NBINS) ccursor[t] = ex;
  }
  if (t == 0) rowptr[N_NODES] = N_EDGES;
}

__global__ __launch_bounds__(256) void scatter_kernel(const int* __restrict__ ei,
                                                      const float* __restrict__ ew,
                                                      int* __restrict__ ccursor,
                                                      uint2* __restrict__ pk,
                                                      unsigned long long* __restrict__ mg0,
                                                      unsigned k00, unsigned k01) {
  if (blockIdx.x >= NTILES) {          // ---- mw0 mask blocks (idle VALU) ----
    int i = (blockIdx.x - NTILES) * 256 + threadIdx.x;
    unsigned o0, o1;
    tf2x32(k00, k01, 0u, (unsigned)i, o0, o1);
    unsigned long long b0 = __ballot(((o0 ^ o1) >> 31) == 0u);
    if ((threadIdx.x & 63) == 0) mg0[i >> 6] = b0;
    return;
  }
  __shared__ uint2 st[TILE];
  __shared__ unsigned short sbin[TILE];
  __shared__ int h[NBINS];
  __shared__ int base[NBINS];
  __shared__ int gbase[NBINS];
  __shared__ int cur[NBINS];
  __shared__ int sc[512];
  const int tid = threadIdx.x;
  const int e0 = blockIdx.x * TILE;
  const int nt = (N_EDGES - e0 < TILE) ? (N_EDGES - e0) : TILE;

  for (int i = tid; i < NBINS; i += 256) { h[i] = 0; cur[i] = 0; }
  __syncthreads();
  for (int j = tid; j < nt; j += 256) {
    int r = ei[e0 + j];
    r = (r < 0) ? 0 : (r >= N_NODES ? N_NODES - 1 : r);
    atomicAdd(&h[r >> 7], 1);
  }
  __syncthreads();
  sc[tid] = (tid < NBINS) ? h[tid] : 0;
  sc[tid + 256] = (tid + 256 < NBINS) ? h[tid + 256] : 0;
  __syncthreads();
  for (int off = 1; off < 512; off <<= 1) {
    int a0 = (tid >= off) ? sc[tid - off] : 0;
    int a1 = (tid + 256 >= off) ? sc[tid + 256 - off] : 0;
    __syncthreads();
    sc[tid] += a0; sc[tid + 256] += a1;
    __syncthreads();
  }
  if (tid < NBINS) {
    base[tid] = sc[tid] - h[tid];
    if (h[tid]) gbase[tid] = atomicAdd(&ccursor[tid], h[tid]);
  }
  if (tid + 256 < NBINS) {
    base[tid + 256] = sc[tid + 256] - h[tid + 256];
    if (h[tid + 256]) gbase[tid + 256] = atomicAdd(&ccursor[tid + 256], h[tid + 256]);
  }
  __syncthreads();
  for (int j = tid; j < nt; j += 256) {
    int r = ei[e0 + j];
    r = (r < 0) ? 0 : (r >= N_NODES ? N_NODES - 1 : r);
    int c = ei[N_EDGES + e0 + j];
    c = (c < 0) ? 0 : (c >= N_NODES ? N_NODES - 1 : c);
    int bb = r >> 7;
    int slot = base[bb] + atomicAdd(&cur[bb], 1);
    uint2 p;
    p.x = ((unsigned)r << 16) | (unsigned)c;
    p.y = __float_as_uint(ew[e0 + j]);
    st[slot] = p;
    sbin[slot] = (unsigned short)bb;
  }
  __syncthreads();
  for (int j = tid; j < nt; j += 256) {
    int bb = sbin[j];
    pk[gbase[bb] + (j - base[bb])] = st[j];
  }
}

__global__ __launch_bounds__(256) void place_kernel(const int* __restrict__ cbase,
                                                    const uint2* __restrict__ pk,
                                                    uint2* __restrict__ csr,
                                                    int* __restrict__ rowptr,
                                                    float* __restrict__ invc) {
  __shared__ int lcnt[128];
  __shared__ int lpre[128];
  __shared__ int lcur[128];
  __shared__ int sc[128];
  const int b = blockIdx.x;
  const int tid = threadIdx.x;
  const int cb = cbase[b];
  const int n = cbase[b + 1] - cb;
  const int r0 = b << 7;
  const int nr = (N_NODES - r0 < 128) ? (N_NODES - r0) : 128;

  if (tid < 128) { lcnt[tid] = 0; lcur[tid] = 0; }
  __syncthreads();
  for (int i = tid; i < n; i += 256) {
    int r7 = (int)(pk[cb + i].x >> 16) - r0;
    atomicAdd(&lcnt[r7], 1);
  }
  __syncthreads();
  if (tid < 128) sc[tid] = lcnt[tid];
  __syncthreads();
  for (int off = 1; off < 128; off <<= 1) {
    int tv = (tid >= off && tid < 128) ? sc[tid - off] : 0;
    __syncthreads();
    if (tid < 128) sc[tid] += tv;
    __syncthreads();
  }
  if (tid < 128) lpre[tid] = sc[tid] - lcnt[tid];
  __syncthreads();
  if (tid < nr) {
    rowptr[r0 + tid] = cb + lpre[tid];
    int c = lcnt[tid];
    invc[r0 + tid] = 1.0f / (float)(c > 1 ? c : 1);
  }
  for (int i = tid; i < n; i += 256) {
    uint2 p = pk[cb + i];
    int r7 = (int)(p.x >> 16) - r0;
    int slot = cb + lpre[r7] + atomicAdd(&lcur[r7], 1);
    uint2 o;
    o.x = p.x & 0xFFFFu;
    o.y = p.y;
    csr[slot] = o;
  }
}

// ---------------------------------------------------------------------------
// Fused layer: gather 64 rows into LDS (R6 agg structure, per-wave), then
// 64x128 MFMA GEMM over [aggT | Hin] @ Wt. Epilogue: +sw*bvec+bagg, ReLU,
// dropout (bit-packed), bf16 store (+fp32 store when L3).
// When MASKGEN, blocks >= GBF generate mw1/mw2 (hidden under MFMA phase).
// ---------------------------------------------------------------------------
template <bool L3, bool MASKGEN>
__global__ __launch_bounds__(256) void fused_layer(
    const unsigned short* __restrict__ Hin,
    const int* __restrict__ rowptr, const uint2* __restrict__ csr,
    const float* __restrict__ invc,
    const unsigned short* __restrict__ Wt,     // [128 cols][256 k] bf16
    const float* __restrict__ bvec, const float* __restrict__ bagg,
    const unsigned long long* __restrict__ maskw,
    float* __restrict__ outf, unsigned short* __restrict__ outb,
    unsigned long long* __restrict__ g1, unsigned long long* __restrict__ g2,
    unsigned k10, unsigned k11, unsigned k20, unsigned k21) {
  if (MASKGEN && blockIdx.x >= GBF) {
    int i = (blockIdx.x - GBF) * 256 + threadIdx.x;
    unsigned o0, o1;
    tf2x32(k10, k11, 0u, (unsigned)i, o0, o1);
    unsigned long long b1 = __ballot(((o0 ^ o1) >> 31) == 0u);
    tf2x32(k20, k21, 0u, (unsigned)i, o0, o1);
    unsigned long long b2 = __ballot(((o0 ^ o1) >> 31) == 0u);
    if ((threadIdx.x & 63) == 0) { g1[i >> 6] = b1; g2[i >> 6] = b2; }
    return;
  }
  constexpr int LA = 136;   // aggT row stride (shorts); 272B rows, bank step 4
  constexpr int LS = 72;    // staging stride (R6-verified)
  __shared__ unsigned short aggT[64 * LA];   // 17.4 KB
  __shared__ unsigned short Als[64 * LS];    // 9.2 KB
  __shared__ unsigned short Bls[128 * LS];   // 18.4 KB
  __shared__ float swL[64];
  const int tid = threadIdx.x;
  const int m0 = blockIdx.x * 64;
  const int lane = tid & 63;
  const int wid = tid >> 6;

  // ---- gather phase: wave handles rows wid, wid+4, ... (R6 agg geometry) ----
  {
    const int es = lane >> 4;
    const int cg = lane & 15;
    const uint4* __restrict__ H4 = (const uint4*)Hin;
    for (int rr = wid; rr < 64; rr += 4) {
      int r = m0 + rr;
      if (r >= N_NODES) r = N_NODES - 1;
      const int start = rowptr[r];
      const int num = rowptr[r + 1] - start;
      float a[8] = {0.f, 0.f, 0.f, 0.f, 0.f, 0.f, 0.f, 0.f};
      float ws = 0.f;
      for (int e = 0; e < num; e += 16) {
#pragma unroll
        for (int j = 0; j < 4; ++j) {
          int idx = e + j * 4 + es;
          bool ok = idx < num;
          int idxc = ok ? idx : (num - 1);
          uint2 q = csr[start + idxc];
          float w = ok ? __uint_as_float(q.y) : 0.0f;
          uint4 p = H4[(size_t)q.x * 16 + cg];
          ws += w;
          a[0] += w * bflo(p.x); a[1] += w * bfhi(p.x);
          a[2] += w * bflo(p.y); a[3] += w * bfhi(p.y);
          a[4] += w * bflo(p.z); a[5] += w * bfhi(p.z);
          a[6] += w * bflo(p.w); a[7] += w * bfhi(p.w);
        }
      }
#pragma unroll
      for (int k = 0; k < 8; ++k) {
        a[k] += __shfl_xor(a[k], 32);
        a[k] += __shfl_xor(a[k], 16);
      }
      ws += __shfl_xor(ws, 32);
      ws += __shfl_xor(ws, 16);
      const float s = invc[r];
      if (es == 0) {
        uint4 o;
        o.x = (unsigned)f2bf(a[0] * s) | ((unsigned)f2bf(a[1] * s) << 16);
        o.y = (unsigned)f2bf(a[2] * s) | ((unsigned)f2bf(a[3] * s) << 16);
        o.z = (unsigned)f2bf(a[4] * s) | ((unsigned)f2bf(a[5] * s) << 16);
        o.w = (unsigned)f2bf(a[6] * s) | ((unsigned)f2bf(a[7] * s) << 16);
        *(uint4*)&aggT[rr * LA + cg * 8] = o;
      }
      if (lane == 0) swL[rr] = ws * s;
    }
  }
  __syncthreads();

  // ---- MFMA phase: wave = 32x64 tile (wm x wn), 2x4 MFMA 16x16x32 ----
  const int wm = (wid >> 1) * 32;
  const int wn = (wid & 1) * 64;
  const int ln = lane & 15;
  const int lh = lane >> 4;
  const int sArow = tid >> 2;
  const int sAk = (tid & 3) * 16;
  const int sBcol = tid >> 1;
  const int sBk = (tid & 1) * 32;
  int arow = m0 + sArow;
  if (arow >= N_NODES) arow = N_NODES - 1;

  f32x4 acc[2][4];
#pragma unroll
  for (int i = 0; i < 2; ++i)
#pragma unroll
    for (int j = 0; j < 4; ++j)
#pragma unroll
      for (int r = 0; r < 4; ++r) acc[i][j][r] = 0.0f;

  for (int kb = 0; kb < 256; kb += 64) {
    if (kb >= 128) {   // stage concat-bottom A rows from Hin
      const unsigned short* ap = Hin + (size_t)arow * 128 + (kb & 127) + sAk;
      unsigned short* al = &Als[sArow * LS + sAk];
      *(uint4*)(al + 0) = *(const uint4*)(ap + 0);
      *(uint4*)(al + 8) = *(const uint4*)(ap + 8);
    }
    {                  // stage B tile (128 cols x 64 k)
      const unsigned short* bp = Wt + (size_t)sBcol * 256 + kb + sBk;
      unsigned short* bl = &Bls[sBcol * LS + sBk];
      *(uint4*)(bl + 0)  = *(const uint4*)(bp + 0);
      *(uint4*)(bl + 8)  = *(const uint4*)(bp + 8);
      *(uint4*)(bl + 16) = *(const uint4*)(bp + 16);
      *(uint4*)(bl + 24) = *(const uint4*)(bp + 24);
    }
    __syncthreads();
#pragma unroll
    for (int ks = 0; ks < 64; ks += 32) {
      bf16x8 af[2], bfr[4];
#pragma unroll
      for (int i = 0; i < 2; ++i)
        af[i] = (kb < 128)
          ? *(const bf16x8*)&aggT[(wm + i * 16 + ln) * LA + kb + ks + lh * 8]
          : *(const bf16x8*)&Als[(wm + i * 16 + ln) * LS + ks + lh * 8];
#pragma unroll
      for (int j = 0; j < 4; ++j)
        bfr[j] = *(const bf16x8*)&Bls[(wn + j * 16 + ln) * LS + ks + lh * 8];
#pragma unroll
      for (int i = 0; i < 2; ++i)
#pragma unroll
        for (int j = 0; j < 4; ++j)
          acc[i][j] = __builtin_amdgcn_mfma_f32_16x16x32_bf16(af[i], bfr[j], acc[i][j], 0, 0, 0);
    }
    __syncthreads();
  }

  // ---- epilogue: C/D map col=lane&15, row=(lane>>4)*4+reg  [m89/m91] ----
  const int lm = lane >> 4;
  float bc[4], b2[4];
#pragma unroll
  for (int j = 0; j < 4; ++j) {
    int col = wn + j * 16 + ln;
    bc[j] = bvec[col];
    b2[j] = bagg[col];
  }
#pragma unroll
  for (int i = 0; i < 2; ++i) {
    const int lr0 = wm + i * 16 + lm * 4;
#pragma unroll
    for (int r = 0; r < 4; ++r) {
      const int lr = lr0 + r;
      const int row = m0 + lr;
      if (row >= N_NODES) continue;
      const float swr = swL[lr];
      const unsigned long long mw = maskw[(size_t)row * 2 + (wn >> 6)];
#pragma unroll
      for (int j = 0; j < 4; ++j) {
        const int col = wn + j * 16 + ln;
        float v = acc[i][j][r] + swr * bc[j] + b2[j];
        v = fmaxf(v, 0.0f);
        v = ((mw >> (col & 63)) & 1ull) ? 2.0f * v : 0.0f;
        if (L3) outf[(size_t)row * DGN + col] = v;
        outb[(size_t)row * DGN + col] = f2bf(v);
      }
    }
  }
}

// ---------------------------------------------------------------------------
// R6-verified 64x64 GEMM (LDS-staged A and B) — used for MLP1 only.
// ---------------------------------------------------------------------------
template <int KTOT, bool RELU>
__global__ __launch_bounds__(256) void mfma_gemm(
    const unsigned short* __restrict__ A0,
    const unsigned short* __restrict__ Wt, const float* __restrict__ bias,
    unsigned short* __restrict__ outb) {
  constexpr int LDK = 72;
  __shared__ unsigned short Als[64 * LDK];
  __shared__ unsigned short Bls[64 * LDK];
  const int tid = threadIdx.x;
  const int mt = blockIdx.x >> 1;
  const int nt = blockIdx.x & 1;
  const int m0 = mt * 64;
  const int lane = tid & 63;
  const int wid = tid >> 6;
  const int wm = (wid >> 1) * 32;
  const int wn = (wid & 1) * 32;
  const int lrow = tid >> 2;
  const int lk = (tid & 3) * 16;

  int arow = m0 + lrow;
  if (arow >= N_NODES) arow = N_NODES - 1;

  f32x4 acc[2][2];
#pragma unroll
  for (int i = 0; i < 2; ++i)
#pragma unroll
    for (int j = 0; j < 2; ++j)
#pragma unroll
      for (int r = 0; r < 4; ++r) acc[i][j][r] = 0.0f;

  for (int kb = 0; kb < KTOT; kb += 64) {
    const unsigned short* ap = A0 + (size_t)arow * 128 + (kb & 127) + lk;
    const unsigned short* bp = Wt + (size_t)(nt * 64 + lrow) * KTOT + kb + lk;
    unsigned short* al = &Als[lrow * LDK + lk];
    unsigned short* bl = &Bls[lrow * LDK + lk];
    *(uint4*)(al + 0) = *(const uint4*)(ap + 0);
    *(uint4*)(al + 8) = *(const uint4*)(ap + 8);
    *(uint4*)(bl + 0) = *(const uint4*)(bp + 0);
    *(uint4*)(bl + 8) = *(const uint4*)(bp + 8);
    __syncthreads();
#pragma unroll
    for (int ks = 0; ks < 64; ks += 32) {
      bf16x8 af[2], bfr[2];
#pragma unroll
      for (int t = 0; t < 2; ++t) {
        af[t]  = *(const bf16x8*)&Als[(wm + t * 16 + (lane & 15)) * LDK + ks + (lane >> 4) * 8];
        bfr[t] = *(const bf16x8*)&Bls[(wn + t * 16 + (lane & 15)) * LDK + ks + (lane >> 4) * 8];
      }
#pragma unroll
      for (int i = 0; i < 2; ++i)
#pragma unroll
        for (int j = 0; j < 2; ++j)
          acc[i][j] = __builtin_amdgcn_mfma_f32_16x16x32_bf16(af[i], bfr[j], acc[i][j], 0, 0, 0);
    }
    __syncthreads();
  }

  const int lm = lane >> 4;
  const int ln = lane & 15;
  float bcol[2];
#pragma unroll
  for (int j = 0; j < 2; ++j) bcol[j] = bias[nt * 64 + wn + j * 16 + ln];

#pragma unroll
  for (int i = 0; i < 2; ++i) {
    const int rbase = m0 + wm + i * 16 + lm * 4;
#pragma unroll
    for (int r = 0; r < 4; ++r) {
      const int row = rbase + r;
      if (row >= N_NODES) continue;
#pragma unroll
      for (int j = 0; j < 2; ++j) {
        const int col = nt * 64 + wn + j * 16 + ln;
        float v = acc[i][j][r] + bcol[j];
        if (RELU) v = fmaxf(v, 0.0f);
        outb[(size_t)row * DGN + col] = f2bf(v);
      }
    }
  }
}

// ---------------------------------------------------------------------------
// MLP head 2: y[N,10] = t[N,128](bf16) @ W2[128,10] + b2.
// ---------------------------------------------------------------------------
__global__ __launch_bounds__(256) void mlp2_kernel(const unsigned short* __restrict__ t,
                                                   const float* __restrict__ W2,
                                                   const float* __restrict__ b2,
                                                   float* __restrict__ y) {
  __shared__ float Ws[128 * DOUT];
  __shared__ float bs[DOUT];
  for (int i = threadIdx.x; i < 128 * DOUT; i += 256) Ws[i] = W2[i];
  if (threadIdx.x < DOUT) bs[threadIdx.x] = b2[threadIdx.x];
  __syncthreads();
  int row = blockIdx.x * 256 + threadIdx.x;
  if (row >= N_NODES) return;
  float acc[DOUT];
#pragma unroll
  for (int c = 0; c < DOUT; ++c) acc[c] = bs[c];
  const uint4* tp = (const uint4*)(t + (size_t)row * 128);
#pragma unroll 4
  for (int k8 = 0; k8 < 16; ++k8) {
    uint4 raw = tp[k8];
    unsigned w[4] = {raw.x, raw.y, raw.z, raw.w};
#pragma unroll
    for (int p = 0; p < 4; ++p) {
      float lo = bflo(w[p]);
      float hi = bfhi(w[p]);
      const float* wr = &Ws[(k8 * 8 + p * 2) * DOUT];
#pragma unroll
      for (int c = 0; c < DOUT; ++c)
        acc[c] += lo * wr[c] + hi * wr[DOUT + c];
    }
  }
  float* yp = y + (size_t)row * DOUT;
#pragma unroll
  for (int c = 0; c < DOUT; ++c) yp[c] = acc[c];
}

// ---------------------------------------------------------------------------
extern "C" void kernel_launch(void* const* d_in, const int* in_sizes, int n_in,
                              void* d_out, int out_size, void* d_ws, size_t ws_size,
                              hipStream_t stream) {
  const float* x        = (const float*)d_in[0];
  const int*   ei       = (const int*)d_in[1];
  const float* ew       = (const float*)d_in[2];
  const float* W_lin_in = (const float*)d_in[3];
  const float* b_lin_in = (const float*)d_in[4];
  const float* W_agg_in = (const float*)d_in[5];
  const float* b_agg_in = (const float*)d_in[6];
  const float* W_lin_h  = (const float*)d_in[7];
  const float* b_lin_h  = (const float*)d_in[8];
  const float* W_agg_h  = (const float*)d_in[9];
  const float* b_agg_h  = (const float*)d_in[10];
  const float* W_mlp1   = (const float*)d_in[11];
  const float* b_mlp1   = (const float*)d_in[12];
  const float* W_mlp2   = (const float*)d_in[13];
  const float* b_mlp2   = (const float*)d_in[14];

  float* hout = (float*)d_out;
  float* yout = hout + (size_t)NELEM;

  char* p = (char*)d_ws;
  auto alloc = [&](size_t bytes) {
    char* q = p;
    p += (bytes + 255) & ~(size_t)255;
    return q;
  };
  int*   chist   = (int*)alloc((size_t)(NBINS + 1) * 4);
  int*   cbase   = (int*)alloc((size_t)(NBINS + 1) * 4);
  int*   ccursor = (int*)alloc((size_t)NBINS * 4);
  int*   rowptr  = (int*)alloc((size_t)(N_NODES + 1) * 4);
  float* invc    = (float*)alloc((size_t)N_NODES * 4);
  uint2* pk      = (uint2*)alloc((size_t)N_EDGES * 8);
  uint2* csr     = (uint2*)alloc((size_t)N_EDGES * 8);
  unsigned short* xb   = (unsigned short*)alloc((size_t)NELEM * 2);
  unsigned short* tmb  = (unsigned short*)alloc((size_t)NELEM * 2);   // mlp1 out
  unsigned short* hA   = (unsigned short*)alloc((size_t)NELEM * 2);
  unsigned short* hB   = (unsigned short*)alloc((size_t)NELEM * 2);
  unsigned long long* mw0 = (unsigned long long*)alloc((size_t)NMASKW * 8);
  unsigned long long* mw1 = (unsigned long long*)alloc((size_t)NMASKW * 8);
  unsigned long long* mw2 = (unsigned long long*)alloc((size_t)NMASKW * 8);
  unsigned short* Tai = (unsigned short*)alloc(32768 * 2);
  unsigned short* Tah = (unsigned short*)alloc(32768 * 2);
  unsigned short* Tm1 = (unsigned short*)alloc(16384 * 2);
  float* bvi = (float*)alloc(128 * 4);
  float* bvh = (float*)alloc(128 * 4);

  unsigned dk[3][2];
  for (unsigned i = 0; i < 3; ++i) tf2x32(0u, 42u, 0u, i, dk[i][0], dk[i][1]);

  const int NB = (N_NODES + 255) / 256;
  const int GB = ((N_NODES + 63) / 64) * 2;   // 1564 (mlp1)

  // ---- prep ----
  hipMemsetAsync(chist, 0, (size_t)(NBINS + 1) * 4, stream);
  mega_kernel<<<MEGA_BLOCKS, 256, 0, stream>>>(
      x, xb, ei, chist, W_lin_in, W_agg_in, W_lin_h, W_agg_h, W_mlp1,
      b_lin_in, b_lin_h, Tai, Tah, Tm1, bvi, bvh);

  // ---- CSR build (+ mw0 mask blocks riding on scatter) ----
  prefix_kernel<<<1, 512, 0, stream>>>(chist, cbase, ccursor, rowptr);
  scatter_kernel<<<NTILES + MK_BLOCKS, 256, 0, stream>>>(
      ei, ew, ccursor, pk, mw0, dk[0][0], dk[0][1]);
  place_kernel<<<NBINS, 256, 0, stream>>>(cbase, pk, csr, rowptr, invc);

  // ---- layer 1 (+ mw1/mw2 mask blocks riding on the MFMA phase) ----
  fused_layer<false, true><<<GBF + MK_BLOCKS, 256, 0, stream>>>(
      xb, rowptr, csr, invc, Tai, bvi, b_agg_in, mw0, nullptr, hA,
      mw1, mw2, dk[1][0], dk[1][1], dk[2][0], dk[2][1]);

  // ---- layer 2 ----
  fused_layer<false, false><<<GBF, 256, 0, stream>>>(
      hA, rowptr, csr, invc, Tah, bvh, b_agg_h, mw1, nullptr, hB,
      nullptr, nullptr, 0, 0, 0, 0);

  // ---- layer 3 (fp32 h to d_out + bf16 for mlp) ----
  fused_layer<true, false><<<GBF, 256, 0, stream>>>(
      hB, rowptr, csr, invc, Tah, bvh, b_agg_h, mw2, hout, hA,
      nullptr, nullptr, 0, 0, 0, 0);

  // ---- MLP head ----
  mfma_gemm<128, true><<<GB, 256, 0, stream>>>(hA, Tm1, b_mlp1, tmb);
  mlp2_kernel<<<NB, 256, 0, stream>>>(tmb, W_mlp2, b_mlp2, yout);
}

// Round 9
// 327.930 us; speedup vs baseline: 1.5044x; 1.5044x over previous
//
#include <hip/hip_runtime.h>
#include <cstdint>
#include <cstddef>

// ---------------------------------------------------------------------------
// ReweightGNN: 3x GraphSAGE-reweight (lmda=1.0) + dropout(0.5) + 2-layer MLP
// N=50000, E=800000, D=128, DOUT=10. Outputs: h [N,128] fp32, y [N,10] fp32.
// R9: R6 skeleton restored (R8 fusion reverted — gather TLP collapse).
//   (a) masks ride on scatter (mw0), gemm1 (mw1), gemm2 (mw2): hosts are
//       MFMA/latency-bound, consumers strictly downstream.
//   (b) layer GEMM tile 64x64 -> 64x128 (A staged once, grid 782, 27.6KB LDS).
//   (c) mlp2 fused into mlp1 epilogue via LDS t-tile (tmb round-trip gone).
// ---------------------------------------------------------------------------

#define N_NODES 50000
#define N_EDGES 800000
#define DGN 128
#define DOUT 10
#define NELEM (N_NODES * DGN)       // 6,400,000
#define NMASKW (NELEM / 64)         // 100,000 uint64 words per mask
#define NBINS 391                   // ceil(50000/128) coarse bins (row>>7)
#define TILE 4096                   // edges per scatter block
#define NTILES ((N_EDGES + TILE - 1) / TILE)   // 196
#define GBF ((N_NODES + 63) / 64)   // 782 gemm blocks (64 rows x 128 cols)
#define MK_BLOCKS 25000             // blocks for one bit-packed mask stream

// mega-kernel block ranges (no masks)
#define XB_BLK 6250                 // x fp32->bf16 (1.6M float4)
#define HI_BLK NTILES
#define WC_BLK 128
#define TR_BLK 192
#define R0 XB_BLK
#define R1 (R0 + HI_BLK)
#define R2 (R1 + WC_BLK)
#define R3 (R2 + TR_BLK)
#define MEGA_BLOCKS (R3 + 1)

#define AB_BLOCKS ((N_NODES + 3) / 4)   // 12500 agg blocks (4 rows each)

typedef __attribute__((ext_vector_type(8))) short bf16x8;
typedef __attribute__((ext_vector_type(4))) float f32x4;

__host__ __device__ static inline unsigned short f2bf(float f) {
  union { float f; unsigned u; } c; c.f = f;
  unsigned u = c.u;
  return (unsigned short)((u + 0x7fffu + ((u >> 16) & 1u)) >> 16);  // RNE
}
__device__ static inline float bflo(unsigned u) { return __uint_as_float(u << 16); }
__device__ static inline float bfhi(unsigned u) { return __uint_as_float(u & 0xffff0000u); }
__device__ static inline float bf2f(unsigned short h) {
  return __uint_as_float(((unsigned)h) << 16);
}

// ---------------------------------------------------------------------------
// threefry2x32 (exact JAX)
// ---------------------------------------------------------------------------
__host__ __device__ static inline void tf2x32(unsigned k0, unsigned k1,
                                              unsigned c0, unsigned c1,
                                              unsigned& o0, unsigned& o1) {
  unsigned ks2 = k0 ^ k1 ^ 0x1BD11BDAu;
  unsigned x0 = c0 + k0;
  unsigned x1 = c1 + k1;
#define TFR(r) { x0 += x1; x1 = (x1 << (r)) | (x1 >> (32 - (r))); x1 ^= x0; }
  TFR(13) TFR(15) TFR(26) TFR(6)
  x0 += k1;  x1 += ks2 + 1u;
  TFR(17) TFR(29) TFR(16) TFR(24)
  x0 += ks2; x1 += k0 + 2u;
  TFR(13) TFR(15) TFR(26) TFR(6)
  x0 += k0;  x1 += k1 + 3u;
  TFR(17) TFR(29) TFR(16) TFR(24)
  x0 += k1;  x1 += ks2 + 4u;
  TFR(13) TFR(15) TFR(26) TFR(6)
  x0 += ks2; x1 += k0 + 5u;
#undef TFR
  o0 = x0; o1 = x1;
}

// one bit-packed mask stream chunk (rider blocks use this)
__device__ static inline void mask_chunk(unsigned long long* __restrict__ gm,
                                         int i, unsigned k0, unsigned k1) {
  unsigned o0, o1;
  tf2x32(k0, k1, 0u, (unsigned)i, o0, o1);
  unsigned long long b = __ballot(((o0 ^ o1) >> 31) == 0u);
  if ((threadIdx.x & 63) == 0) gm[i >> 6] = b;
}

// ---------------------------------------------------------------------------
// Mega prep kernel: x convert | hist | W_comb | transposes | bvec
// ---------------------------------------------------------------------------
__global__ __launch_bounds__(256) void mega_kernel(
    const float* __restrict__ x, unsigned short* __restrict__ xb,
    const int* __restrict__ ei, int* __restrict__ chist,
    const float* __restrict__ Wli, const float* __restrict__ Wai,
    const float* __restrict__ Wlh, const float* __restrict__ Wah,
    const float* __restrict__ Wm1,
    const float* __restrict__ bli, const float* __restrict__ blh,
    unsigned short* __restrict__ Tai, unsigned short* __restrict__ Tah,
    unsigned short* __restrict__ Tm1,
    float* __restrict__ bvi, float* __restrict__ bvh) {
  __shared__ int h[NBINS];
  const int b = blockIdx.x;
  const int tid = threadIdx.x;

  if (b < R0) {                       // ---- x convert ----
    int g = b * 256 + tid;
    float4 v = ((const float4*)x)[g];
    ushort4 o;
    o.x = f2bf(v.x); o.y = f2bf(v.y); o.z = f2bf(v.z); o.w = f2bf(v.w);
    ((ushort4*)xb)[g] = o;
  } else if (b < R1) {                // ---- hist ----
    for (int i = tid; i < NBINS; i += 256) h[i] = 0;
    __syncthreads();
    const int e0 = (b - R0) * TILE;
#pragma unroll 4
    for (int j = 0; j < TILE; j += 256) {
      int e = e0 + j + tid;
      if (e < N_EDGES) {
        int r = ei[e];
        r = (r < 0) ? 0 : (r >= N_NODES ? N_NODES - 1 : r);
        atomicAdd(&h[r >> 7], 1);
      }
    }
    __syncthreads();
    for (int i = tid; i < NBINS; i += 256)
      if (h[i]) atomicAdd(&chist[i], h[i]);
  } else if (b < R2) {                // ---- W_comb (fp32 accumulate) ----
    int idx = (b - R1) * 256 + tid;   // [0, 32768)
    int n = idx & 127;
    int k = (idx >> 7) & 127;
    int m = idx >> 14;                // 0: in-layer, 1: hidden
    const float* Wl = m ? Wlh : Wli;
    const float* Wa = m ? Wah : Wai;
    unsigned short* T = m ? Tah : Tai;
    float acc = 0.0f;
#pragma unroll 8
    for (int j = 0; j < 128; ++j)
      acc += Wl[k * 128 + j] * Wa[j * 128 + n];
    T[n * 256 + k] = f2bf(acc);
  } else if (b < R3) {                // ---- transposes ----
    int j = (b - R2) * 256 + tid;     // [0, 49152)
    if (j < 16384) {
      int kk = j & 127, n = j >> 7;
      Tai[n * 256 + 128 + kk] = f2bf(Wai[(size_t)(128 + kk) * 128 + n]);
    } else if (j < 32768) {
      int q = j - 16384;
      int kk = q & 127, n = q >> 7;
      Tah[n * 256 + 128 + kk] = f2bf(Wah[(size_t)(128 + kk) * 128 + n]);
    } else {
      int q = j - 32768;
      int k = q & 127, n = q >> 7;
      Tm1[n * 128 + k] = f2bf(Wm1[(size_t)k * 128 + n]);
    }
  } else {                            // ---- bvec ----
    int n = tid & 127;
    const float* bl = (tid < 128) ? bli : blh;
    const float* Wa = (tid < 128) ? Wai : Wah;
    float acc = 0.0f;
    for (int j = 0; j < 128; ++j) acc += bl[j] * Wa[j * 128 + n];
    if (tid < 128) bvi[n] = acc; else bvh[n] = acc;
  }
}

// ---------------------------------------------------------------------------
// CSR build (verified R5/R6). scatter hosts mw0 rider blocks.
// ---------------------------------------------------------------------------
__global__ __launch_bounds__(512) void prefix_kernel(const int* __restrict__ chist,
                                                     int* __restrict__ cbase,
                                                     int* __restrict__ ccursor,
                                                     int* __restrict__ rowptr) {
  __shared__ int s[512];
  const int t = threadIdx.x;
  int v = (t < NBINS) ? chist[t] : 0;
  s[t] = v;
  __syncthreads();
  for (int off = 1; off < 512; off <<= 1) {
    int tv = (t >= off) ? s[t - off] : 0;
    __syncthreads();
    s[t] += tv;
    __syncthreads();
  }
  if (t <= NBINS) {
    int ex = (t == 0) ? 0 : s[t - 1];
    cbase[t] = ex;
    if (t < NBINS) ccursor[t] = ex;
  }
  if (t == 0) rowptr[N_NODES] = N_EDGES;
}

__global__ __launch_bounds__(256) void scatter_kernel(const int* __restrict__ ei,
                                                      const float* __restrict__ ew,
                                                      int* __restrict__ ccursor,
                                                      uint2* __restrict__ pk,
                                                      unsigned long long* __restrict__ mg0,
                                                      unsigned k00, unsigned k01) {
  if (blockIdx.x >= NTILES) {          // ---- mw0 rider blocks ----
    mask_chunk(mg0, (blockIdx.x - NTILES) * 256 + threadIdx.x, k00, k01);
    return;
  }
  __shared__ uint2 st[TILE];
  __shared__ unsigned short sbin[TILE];
  __shared__ int h[NBINS];
  __shared__ int base[NBINS];
  __shared__ int gbase[NBINS];
  __shared__ int cur[NBINS];
  __shared__ int sc[512];
  const int tid = threadIdx.x;
  const int e0 = blockIdx.x * TILE;
  const int nt = (N_EDGES - e0 < TILE) ? (N_EDGES - e0) : TILE;

  for (int i = tid; i < NBINS; i += 256) { h[i] = 0; cur[i] = 0; }
  __syncthreads();
  for (int j = tid; j < nt; j += 256) {
    int r = ei[e0 + j];
    r = (r < 0) ? 0 : (r >= N_NODES ? N_NODES - 1 : r);
    atomicAdd(&h[r >> 7], 1);
  }
  __syncthreads();
  sc[tid] = (tid < NBINS) ? h[tid] : 0;
  sc[tid + 256] = (tid + 256 < NBINS) ? h[tid + 256] : 0;
  __syncthreads();
  for (int off = 1; off < 512; off <<= 1) {
    int a0 = (tid >= off) ? sc[tid - off] : 0;
    int a1 = (tid + 256 >= off) ? sc[tid + 256 - off] : 0;
    __syncthreads();
    sc[tid] += a0; sc[tid + 256] += a1;
    __syncthreads();
  }
  if (tid < NBINS) {
    base[tid] = sc[tid] - h[tid];
    if (h[tid]) gbase[tid] = atomicAdd(&ccursor[tid], h[tid]);
  }
  if (tid + 256 < NBINS) {
    base[tid + 256] = sc[tid + 256] - h[tid + 256];
    if (h[tid + 256]) gbase[tid + 256] = atomicAdd(&ccursor[tid + 256], h[tid + 256]);
  }
  __syncthreads();
  for (int j = tid; j < nt; j += 256) {
    int r = ei[e0 + j];
    r = (r < 0) ? 0 : (r >= N_NODES ? N_NODES - 1 : r);
    int c = ei[N_EDGES + e0 + j];
    c = (c < 0) ? 0 : (c >= N_NODES ? N_NODES - 1 : c);
    int bb = r >> 7;
    int slot = base[bb] + atomicAdd(&cur[bb], 1);
    uint2 p;
    p.x = ((unsigned)r << 16) | (unsigned)c;
    p.y = __float_as_uint(ew[e0 + j]);
    st[slot] = p;
    sbin[slot] = (unsigned short)bb;
  }
  __syncthreads();
  for (int j = tid; j < nt; j += 256) {
    int bb = sbin[j];
    pk[gbase[bb] + (j - base[bb])] = st[j];
  }
}

__global__ __launch_bounds__(256) void place_kernel(const int* __restrict__ cbase,
                                                    const uint2* __restrict__ pk,
                                                    uint2* __restrict__ csr,
                                                    int* __restrict__ rowptr,
                                                    float* __restrict__ invc) {
  __shared__ int lcnt[128];
  __shared__ int lpre[128];
  __shared__ int lcur[128];
  __shared__ int sc[128];
  const int b = blockIdx.x;
  const int tid = threadIdx.x;
  const int cb = cbase[b];
  const int n = cbase[b + 1] - cb;
  const int r0 = b << 7;
  const int nr = (N_NODES - r0 < 128) ? (N_NODES - r0) : 128;

  if (tid < 128) { lcnt[tid] = 0; lcur[tid] = 0; }
  __syncthreads();
  for (int i = tid; i < n; i += 256) {
    int r7 = (int)(pk[cb + i].x >> 16) - r0;
    atomicAdd(&lcnt[r7], 1);
  }
  __syncthreads();
  if (tid < 128) sc[tid] = lcnt[tid];
  __syncthreads();
  for (int off = 1; off < 128; off <<= 1) {
    int tv = (tid >= off && tid < 128) ? sc[tid - off] : 0;
    __syncthreads();
    if (tid < 128) sc[tid] += tv;
    __syncthreads();
  }
  if (tid < 128) lpre[tid] = sc[tid] - lcnt[tid];
  __syncthreads();
  if (tid < nr) {
    rowptr[r0 + tid] = cb + lpre[tid];
    int c = lcnt[tid];
    invc[r0 + tid] = 1.0f / (float)(c > 1 ? c : 1);
  }
  for (int i = tid; i < n; i += 256) {
    uint2 p = pk[cb + i];
    int r7 = (int)(p.x >> 16) - r0;
    int slot = cb + lpre[r7] + atomicAdd(&lcur[r7], 1);
    uint2 o;
    o.x = p.x & 0xFFFFu;
    o.y = p.y;
    csr[slot] = o;
  }
}

// ---------------------------------------------------------------------------
// Aggregation (R6-verified): one wave per row, uint4 gathers, 4 edges
// wave-parallel, unroll 4, shfl_xor reduce. Emits sw when swout != null.
// ---------------------------------------------------------------------------
__global__ __launch_bounds__(256) void agg_kernel(const unsigned short* __restrict__ hlin,
                                                  const int* __restrict__ rowptr,
                                                  const uint2* __restrict__ csr,
                                                  const float* __restrict__ invc,
                                                  unsigned short* __restrict__ agg,
                                                  float* __restrict__ swout) {
  const int r = blockIdx.x * 4 + (threadIdx.x >> 6);
  const int lane = threadIdx.x & 63;
  const int es = lane >> 4;
  const int cg = lane & 15;
  const int start = rowptr[r];
  const int num = rowptr[r + 1] - start;
  const uint4* __restrict__ H = (const uint4*)hlin;   // 16 uint4 per row

  float a[8] = {0.f, 0.f, 0.f, 0.f, 0.f, 0.f, 0.f, 0.f};
  float ws = 0.f;
  for (int e = 0; e < num; e += 16) {
#pragma unroll
    for (int j = 0; j < 4; ++j) {
      int idx = e + j * 4 + es;
      bool ok = idx < num;
      int idxc = ok ? idx : (num - 1);
      uint2 q = csr[start + idxc];
      float w = ok ? __uint_as_float(q.y) : 0.0f;
      uint4 p = H[(size_t)q.x * 16 + cg];
      ws += w;
      a[0] += w * bflo(p.x); a[1] += w * bfhi(p.x);
      a[2] += w * bflo(p.y); a[3] += w * bfhi(p.y);
      a[4] += w * bflo(p.z); a[5] += w * bfhi(p.z);
      a[6] += w * bflo(p.w); a[7] += w * bfhi(p.w);
    }
  }
#pragma unroll
  for (int k = 0; k < 8; ++k) {
    a[k] += __shfl_xor(a[k], 32);
    a[k] += __shfl_xor(a[k], 16);
  }
  ws += __shfl_xor(ws, 32);
  ws += __shfl_xor(ws, 16);
  const float s = invc[r];
  if (es == 0) {
    uint4 o;
    o.x = (unsigned)f2bf(a[0] * s) | ((unsigned)f2bf(a[1] * s) << 16);
    o.y = (unsigned)f2bf(a[2] * s) | ((unsigned)f2bf(a[3] * s) << 16);
    o.z = (unsigned)f2bf(a[4] * s) | ((unsigned)f2bf(a[5] * s) << 16);
    o.w = (unsigned)f2bf(a[6] * s) | ((unsigned)f2bf(a[7] * s) << 16);
    ((uint4*)agg)[(size_t)r * 16 + cg] = o;
  }
  if (swout && lane == 0) swout[r] = ws * s;
}

// ---------------------------------------------------------------------------
// Layer GEMM, 64 rows x 128 cols (full N in one block), K=256 over
// [Agg | Hin] @ Wt. Wave = 32x64 tile = 2x4 MFMA 16x16x32 (R8 MFMA phase,
// correctness-verified). Epilogue: +sw*bvec+bagg, ReLU, bit-packed dropout,
// bf16 store (+fp32 when WF32). Blocks >= GBF (when MASKGEN): one mask stream.
// ---------------------------------------------------------------------------
template <bool WF32, bool MASKGEN>
__global__ __launch_bounds__(256) void layer_gemm(
    const unsigned short* __restrict__ Agg, const unsigned short* __restrict__ Hin,
    const unsigned short* __restrict__ Wt,   // [128 cols][256 k] bf16
    const float* __restrict__ bvec, const float* __restrict__ bagg,
    const float* __restrict__ sw,
    const unsigned long long* __restrict__ maskw,
    float* __restrict__ outf, unsigned short* __restrict__ outb,
    unsigned long long* __restrict__ gm, unsigned gk0, unsigned gk1) {
  if (MASKGEN && blockIdx.x >= GBF) {
    mask_chunk(gm, (blockIdx.x - GBF) * 256 + threadIdx.x, gk0, gk1);
    return;
  }
  constexpr int LS = 72;
  __shared__ unsigned short Als[64 * LS];    // 9.2 KB
  __shared__ unsigned short Bls[128 * LS];   // 18.4 KB
  const int tid = threadIdx.x;
  const int m0 = blockIdx.x * 64;
  const int lane = tid & 63;
  const int wid = tid >> 6;
  const int wm = (wid >> 1) * 32;
  const int wn = (wid & 1) * 64;
  const int ln = lane & 15;
  const int lh = lane >> 4;
  const int sArow = tid >> 2;
  const int sAk = (tid & 3) * 16;
  const int sBcol = tid >> 1;
  const int sBk = (tid & 1) * 32;
  int arow = m0 + sArow;
  if (arow >= N_NODES) arow = N_NODES - 1;

  f32x4 acc[2][4];
#pragma unroll
  for (int i = 0; i < 2; ++i)
#pragma unroll
    for (int j = 0; j < 4; ++j)
#pragma unroll
      for (int r = 0; r < 4; ++r) acc[i][j][r] = 0.0f;

  for (int kb = 0; kb < 256; kb += 64) {
    const unsigned short* Asrc = (kb < 128) ? Agg : Hin;
    const unsigned short* ap = Asrc + (size_t)arow * 128 + (kb & 127) + sAk;
    unsigned short* al = &Als[sArow * LS + sAk];
    *(uint4*)(al + 0) = *(const uint4*)(ap + 0);
    *(uint4*)(al + 8) = *(const uint4*)(ap + 8);
    const unsigned short* bp = Wt + (size_t)sBcol * 256 + kb + sBk;
    unsigned short* bl = &Bls[sBcol * LS + sBk];
    *(uint4*)(bl + 0)  = *(const uint4*)(bp + 0);
    *(uint4*)(bl + 8)  = *(const uint4*)(bp + 8);
    *(uint4*)(bl + 16) = *(const uint4*)(bp + 16);
    *(uint4*)(bl + 24) = *(const uint4*)(bp + 24);
    __syncthreads();
#pragma unroll
    for (int ks = 0; ks < 64; ks += 32) {
      bf16x8 af[2], bfr[4];
#pragma unroll
      for (int i = 0; i < 2; ++i)
        af[i] = *(const bf16x8*)&Als[(wm + i * 16 + ln) * LS + ks + lh * 8];
#pragma unroll
      for (int j = 0; j < 4; ++j)
        bfr[j] = *(const bf16x8*)&Bls[(wn + j * 16 + ln) * LS + ks + lh * 8];
#pragma unroll
      for (int i = 0; i < 2; ++i)
#pragma unroll
        for (int j = 0; j < 4; ++j)
          acc[i][j] = __builtin_amdgcn_mfma_f32_16x16x32_bf16(af[i], bfr[j], acc[i][j], 0, 0, 0);
    }
    __syncthreads();
  }

  // epilogue: C/D map col=lane&15, row=(lane>>4)*4+reg  [m89/m91]
  const int lm = lane >> 4;
  float bc[4], b2[4];
#pragma unroll
  for (int j = 0; j < 4; ++j) {
    int col = wn + j * 16 + ln;
    bc[j] = bvec[col];
    b2[j] = bagg[col];
  }
#pragma unroll
  for (int i = 0; i < 2; ++i) {
    const int lr0 = wm + i * 16 + lm * 4;
#pragma unroll
    for (int r = 0; r < 4; ++r) {
      const int row = m0 + lr0 + r;
      if (row >= N_NODES) continue;
      const float swr = sw[row];
      const unsigned long long mw = maskw[(size_t)row * 2 + (wn >> 6)];
#pragma unroll
      for (int j = 0; j < 4; ++j) {
        const int col = wn + j * 16 + ln;
        float v = acc[i][j][r] + swr * bc[j] + b2[j];
        v = fmaxf(v, 0.0f);
        v = ((mw >> (col & 63)) & 1ull) ? 2.0f * v : 0.0f;
        if (WF32) outf[(size_t)row * DGN + col] = v;
        outb[(size_t)row * DGN + col] = f2bf(v);
      }
    }
  }
}

// ---------------------------------------------------------------------------
// MLP GEMM: t = relu(hA @ Wm1 + b1) into an LDS tile (never hits global),
// then per-row mlp2: y = bf16(t) @ W2 + b2. 64 rows x 128 cols, K=128.
// ---------------------------------------------------------------------------
__global__ __launch_bounds__(256) void mlp_gemm(
    const unsigned short* __restrict__ A0,
    const unsigned short* __restrict__ Wt,   // Tm1 [128 cols][128 k]
    const float* __restrict__ b1,
    const float* __restrict__ W2, const float* __restrict__ b2,
    float* __restrict__ y) {
  constexpr int LS = 72;
  constexpr int LT = 132;
  __shared__ unsigned short Als[64 * LS];     // 9.2 KB
  __shared__ unsigned short Bls[128 * LS];    // 18.4 KB
  __shared__ unsigned short tT[64 * LT];      // 16.9 KB
  __shared__ float Ws[128 * DOUT];            // 5.1 KB
  __shared__ float bs[DOUT];
  const int tid = threadIdx.x;
  const int m0 = blockIdx.x * 64;
  const int lane = tid & 63;
  const int wid = tid >> 6;
  const int wm = (wid >> 1) * 32;
  const int wn = (wid & 1) * 64;
  const int ln = lane & 15;
  const int lh = lane >> 4;
  const int sArow = tid >> 2;
  const int sAk = (tid & 3) * 16;
  const int sBcol = tid >> 1;
  const int sBk = (tid & 1) * 32;
  int arow = m0 + sArow;
  if (arow >= N_NODES) arow = N_NODES - 1;

  for (int i = tid; i < 128 * DOUT; i += 256) Ws[i] = W2[i];
  if (tid < DOUT) bs[tid] = b2[tid];

  f32x4 acc[2][4];
#pragma unroll
  for (int i = 0; i < 2; ++i)
#pragma unroll
    for (int j = 0; j < 4; ++j)
#pragma unroll
      for (int r = 0; r < 4; ++r) acc[i][j][r] = 0.0f;

  for (int kb = 0; kb < 128; kb += 64) {
    const unsigned short* ap = A0 + (size_t)arow * 128 + kb + sAk;
    unsigned short* al = &Als[sArow * LS + sAk];
    *(uint4*)(al + 0) = *(const uint4*)(ap + 0);
    *(uint4*)(al + 8) = *(const uint4*)(ap + 8);
    const unsigned short* bp = Wt + (size_t)sBcol * 128 + kb + sBk;
    unsigned short* bl = &Bls[sBcol * LS + sBk];
    *(uint4*)(bl + 0)  = *(const uint4*)(bp + 0);
    *(uint4*)(bl + 8)  = *(const uint4*)(bp + 8);
    *(uint4*)(bl + 16) = *(const uint4*)(bp + 16);
    *(uint4*)(bl + 24) = *(const uint4*)(bp + 24);
    __syncthreads();
#pragma unroll
    for (int ks = 0; ks < 64; ks += 32) {
      bf16x8 af[2], bfr[4];
#pragma unroll
      for (int i = 0; i < 2; ++i)
        af[i] = *(const bf16x8*)&Als[(wm + i * 16 + ln) * LS + ks + lh * 8];
#pragma unroll
      for (int j = 0; j < 4; ++j)
        bfr[j] = *(const bf16x8*)&Bls[(wn + j * 16 + ln) * LS + ks + lh * 8];
#pragma unroll
      for (int i = 0; i < 2; ++i)
#pragma unroll
        for (int j = 0; j < 4; ++j)
          acc[i][j] = __builtin_amdgcn_mfma_f32_16x16x32_bf16(af[i], bfr[j], acc[i][j], 0, 0, 0);
    }
    __syncthreads();
  }

  // epilogue -> LDS t-tile (bf16, matches R6's tmb numerics)
  const int lm = lane >> 4;
  float bcol[4];
#pragma unroll
  for (int j = 0; j < 4; ++j) bcol[j] = b1[wn + j * 16 + ln];
#pragma unroll
  for (int i = 0; i < 2; ++i) {
    const int lr0 = wm + i * 16 + lm * 4;
#pragma unroll
    for (int r = 0; r < 4; ++r) {
      const int lr = lr0 + r;
#pragma unroll
      for (int j = 0; j < 4; ++j) {
        const int col = wn + j * 16 + ln;
        float v = fmaxf(acc[i][j][r] + bcol[j], 0.0f);
        tT[lr * LT + col] = f2bf(v);
      }
    }
  }
  __syncthreads();

  // mlp2: thread t < 64 handles row t
  if (tid < 64) {
    int row = m0 + tid;
    if (row < N_NODES) {
      float a2[DOUT];
#pragma unroll
      for (int c = 0; c < DOUT; ++c) a2[c] = bs[c];
      const unsigned short* tr = &tT[tid * LT];
#pragma unroll 8
      for (int k = 0; k < 128; ++k) {
        float tv = bf2f(tr[k]);
        const float* wr = &Ws[k * DOUT];
#pragma unroll
        for (int c = 0; c < DOUT; ++c) a2[c] += tv * wr[c];
      }
      float* yp = y + (size_t)row * DOUT;
#pragma unroll
      for (int c = 0; c < DOUT; ++c) yp[c] = a2[c];
    }
  }
}

// ---------------------------------------------------------------------------
extern "C" void kernel_launch(void* const* d_in, const int* in_sizes, int n_in,
                              void* d_out, int out_size, void* d_ws, size_t ws_size,
                              hipStream_t stream) {
  const float* x        = (const float*)d_in[0];
  const int*   ei       = (const int*)d_in[1];
  const float* ew       = (const float*)d_in[2];
  const float* W_lin_in = (const float*)d_in[3];
  const float* b_lin_in = (const float*)d_in[4];
  const float* W_agg_in = (const float*)d_in[5];
  const float* b_agg_in = (const float*)d_in[6];
  const float* W_lin_h  = (const float*)d_in[7];
  const float* b_lin_h  = (const float*)d_in[8];
  const float* W_agg_h  = (const float*)d_in[9];
  const float* b_agg_h  = (const float*)d_in[10];
  const float* W_mlp1   = (const float*)d_in[11];
  const float* b_mlp1   = (const float*)d_in[12];
  const float* W_mlp2   = (const float*)d_in[13];
  const float* b_mlp2   = (const float*)d_in[14];

  float* hout = (float*)d_out;
  float* yout = hout + (size_t)NELEM;

  char* p = (char*)d_ws;
  auto alloc = [&](size_t bytes) {
    char* q = p;
    p += (bytes + 255) & ~(size_t)255;
    return q;
  };
  int*   chist   = (int*)alloc((size_t)(NBINS + 1) * 4);
  int*   cbase   = (int*)alloc((size_t)(NBINS + 1) * 4);
  int*   ccursor = (int*)alloc((size_t)NBINS * 4);
  int*   rowptr  = (int*)alloc((size_t)(N_NODES + 1) * 4);
  float* invc    = (float*)alloc((size_t)N_NODES * 4);
  float* swv     = (float*)alloc((size_t)N_NODES * 4);
  uint2* pk      = (uint2*)alloc((size_t)N_EDGES * 8);
  uint2* csr     = (uint2*)alloc((size_t)N_EDGES * 8);
  unsigned short* xb   = (unsigned short*)alloc((size_t)NELEM * 2);
  unsigned short* aggb = (unsigned short*)alloc((size_t)NELEM * 2);
  unsigned short* hA   = (unsigned short*)alloc((size_t)NELEM * 2);
  unsigned short* hB   = (unsigned short*)alloc((size_t)NELEM * 2);
  unsigned long long* mw0 = (unsigned long long*)alloc((size_t)NMASKW * 8);
  unsigned long long* mw1 = (unsigned long long*)alloc((size_t)NMASKW * 8);
  unsigned long long* mw2 = (unsigned long long*)alloc((size_t)NMASKW * 8);
  unsigned short* Tai = (unsigned short*)alloc(32768 * 2);
  unsigned short* Tah = (unsigned short*)alloc(32768 * 2);
  unsigned short* Tm1 = (unsigned short*)alloc(16384 * 2);
  float* bvi = (float*)alloc(128 * 4);
  float* bvh = (float*)alloc(128 * 4);

  unsigned dk[3][2];
  for (unsigned i = 0; i < 3; ++i) tf2x32(0u, 42u, 0u, i, dk[i][0], dk[i][1]);

  // ---- prep ----
  hipMemsetAsync(chist, 0, (size_t)(NBINS + 1) * 4, stream);
  mega_kernel<<<MEGA_BLOCKS, 256, 0, stream>>>(
      x, xb, ei, chist, W_lin_in, W_agg_in, W_lin_h, W_agg_h, W_mlp1,
      b_lin_in, b_lin_h, Tai, Tah, Tm1, bvi, bvh);

  // ---- CSR build (+ mw0 riders) ----
  prefix_kernel<<<1, 512, 0, stream>>>(chist, cbase, ccursor, rowptr);
  scatter_kernel<<<NTILES + MK_BLOCKS, 256, 0, stream>>>(
      ei, ew, ccursor, pk, mw0, dk[0][0], dk[0][1]);
  place_kernel<<<NBINS, 256, 0, stream>>>(cbase, pk, csr, rowptr, invc);

  // ---- layer 1 (+ mw1 riders on gemm1) ----
  agg_kernel<<<AB_BLOCKS, 256, 0, stream>>>(xb, rowptr, csr, invc, aggb, swv);
  layer_gemm<false, true><<<GBF + MK_BLOCKS, 256, 0, stream>>>(
      aggb, xb, Tai, bvi, b_agg_in, swv, mw0, nullptr, hA,
      mw1, dk[1][0], dk[1][1]);

  // ---- layer 2 (+ mw2 riders on gemm2) ----
  agg_kernel<<<AB_BLOCKS, 256, 0, stream>>>(hA, rowptr, csr, invc, aggb, nullptr);
  layer_gemm<false, true><<<GBF + MK_BLOCKS, 256, 0, stream>>>(
      aggb, hA, Tah, bvh, b_agg_h, swv, mw1, nullptr, hB,
      mw2, dk[2][0], dk[2][1]);

  // ---- layer 3 (fp32 h to d_out + bf16 for mlp) ----
  agg_kernel<<<AB_BLOCKS, 256, 0, stream>>>(hB, rowptr, csr, invc, aggb, nullptr);
  layer_gemm<true, false><<<GBF, 256, 0, stream>>>(
      aggb, hB, Tah, bvh, b_agg_h, swv, mw2, hout, hA,
      nullptr, 0, 0);

  // ---- MLP head (mlp2 fused in-block) ----
  mlp_gemm<<<GBF, 256, 0, stream>>>(hA, Tm1, b_mlp1, W_mlp2, b_mlp2, yout);
}